// Round 8
// baseline (178.506 us; speedup 1.0000x reference)
//
#include <hip/hip_runtime.h>
#include <hip/hip_bf16.h>
#include <cstdint>

typedef unsigned short ushort_t;
typedef __bf16 bf16x8 __attribute__((ext_vector_type(8)));
typedef float f32x4 __attribute__((ext_vector_type(4)));

#define B_   16
#define S_   512
#define D_   768
#define E_   128
#define R_   2048
#define NREL 32768

__device__ inline ushort_t f2b(float f) {
    uint32_t u = __builtin_bit_cast(uint32_t, f);
    uint32_t r = (u + 0x7fffu + ((u >> 16) & 1u)) >> 16;   // RNE
    return (ushort_t)r;
}
__device__ inline float b2f(ushort_t u) {
    uint32_t v = ((uint32_t)u) << 16;
    return __builtin_bit_cast(float, v);
}
__device__ inline float bl(uint32_t u) {
    uint32_t v = u << 16;
    return __builtin_bit_cast(float, v);
}
__device__ inline float bh(uint32_t u) {
    uint32_t v = u & 0xffff0000u;
    return __builtin_bit_cast(float, v);
}

// ---------------------------------------------------------------------------
// Fused prep: one dispatch replaces prep_kernel + transpose_w.
// Block ranges (dispatch order -> biasE latency-stragglers start first):
//   [0,24):    biasE[l] = b1 + emb[l] @ W1_bottom (full-K per block)
//   [24,1566): repE float4 gather -> bf16, BmatT rows 768/769, lWtT, out[0]=0
//   [1566,3582): six 32x32-tiled fp32->bf16 transposes (W1-top, W2, bil)
// ---------------------------------------------------------------------------
#define NB_BIAS 24
#define NB_PREP 1542

__global__ __launch_bounds__(256) void prep_fused(
    const float* __restrict__ hidden, const float* __restrict__ emb,
    const float* __restrict__ lW,
    const float* __restrict__ hW1, const float* __restrict__ tW1,
    const float* __restrict__ hW2, const float* __restrict__ tW2,
    const float* __restrict__ bil,
    const float* __restrict__ hb1, const float* __restrict__ tb1,
    const int* __restrict__ ent_start,
    ushort_t* __restrict__ repE,
    ushort_t* __restrict__ hW1T, ushort_t* __restrict__ tW1T,
    ushort_t* __restrict__ hW2T, ushort_t* __restrict__ tW2T,
    ushort_t* __restrict__ BmatT, ushort_t* __restrict__ lWtT,
    float* __restrict__ biasEh, float* __restrict__ biasEt,
    float* __restrict__ out)
{
    __shared__ float smem[3072];
    int bid = blockIdx.x;
    int tid = threadIdx.x;

    if (bid < NB_BIAS) {
        // 12 col-blocks of 64 cols x 2 towers; 16 k-groups of 48 rows each.
        int tower = bid / 12, cb = bid - tower * 12;
        const float* W1 = tower ? tW1 : hW1;
        const float* b1 = tower ? tb1 : hb1;
        float* dstB     = tower ? biasEt : biasEh;
        int c4 = (tid & 15) * 4;              // col quad within the 64
        int kg = tid >> 4;                    // 16 k-groups
        int col0 = cb * 64;
        const float* wp = W1 + (size_t)(768 + kg * 48) * 768 + col0 + c4;
        const float* ep = emb + kg * 48;
        float a0x = 0.f, a0y = 0.f, a0z = 0.f, a0w = 0.f;
        float a1x = 0.f, a1y = 0.f, a1z = 0.f, a1w = 0.f;
        float a2x = 0.f, a2y = 0.f, a2z = 0.f, a2w = 0.f;
#pragma unroll 8
        for (int k = 0; k < 48; ++k) {
            float4 w = *reinterpret_cast<const float4*>(wp + (size_t)k * 768);
            float e0 = ep[k], e1 = ep[768 + k], e2 = ep[1536 + k];
            a0x += e0 * w.x; a0y += e0 * w.y; a0z += e0 * w.z; a0w += e0 * w.w;
            a1x += e1 * w.x; a1y += e1 * w.y; a1z += e1 * w.z; a1w += e1 * w.w;
            a2x += e2 * w.x; a2y += e2 * w.y; a2z += e2 * w.z; a2w += e2 * w.w;
        }
        smem[kg * 192 +   0 + c4 + 0] = a0x;
        smem[kg * 192 +   0 + c4 + 1] = a0y;
        smem[kg * 192 +   0 + c4 + 2] = a0z;
        smem[kg * 192 +   0 + c4 + 3] = a0w;
        smem[kg * 192 +  64 + c4 + 0] = a1x;
        smem[kg * 192 +  64 + c4 + 1] = a1y;
        smem[kg * 192 +  64 + c4 + 2] = a1z;
        smem[kg * 192 +  64 + c4 + 3] = a1w;
        smem[kg * 192 + 128 + c4 + 0] = a2x;
        smem[kg * 192 + 128 + c4 + 1] = a2y;
        smem[kg * 192 + 128 + c4 + 2] = a2z;
        smem[kg * 192 + 128 + c4 + 3] = a2w;
        __syncthreads();
        if (tid < 192) {
            int l = tid >> 6, c = tid & 63;
            float s = 0.f;
#pragma unroll
            for (int g = 0; g < 16; ++g) s += smem[g * 192 + l * 64 + c];
            dstB[l * 768 + col0 + c] = b1[col0 + c] + s;
        }
        return;
    }

    int pb = bid - NB_BIAS;
    if (pb < NB_PREP) {
        int idx = pb * 256 + tid;
        if (idx == 0) out[0] = 0.0f;
        if (idx < 393216) {                  // repE [2048,768] via float4
            int row = idx / 192, q = idx - row * 192;
            int c = q * 4;
            int b = row >> 7;
            int st = ent_start[row];
            const float* srcp = hidden + ((size_t)(b * S_ + st) * D_ + c);
            float4 v = *reinterpret_cast<const float4*>(srcp);
            uint32_t lo = (uint32_t)f2b(v.x) | ((uint32_t)f2b(v.y) << 16);
            uint32_t hi = (uint32_t)f2b(v.z) | ((uint32_t)f2b(v.w) << 16);
            uint2 pk; pk.x = lo; pk.y = hi;
            *reinterpret_cast<uint2*>(repE + (size_t)idx * 4) = pk;
            return;
        }
        int i2 = idx - 393216;
        if (i2 < 768) {                      // BmatT rows 768/769 (head-linear)
            int o = i2 / 384, kk = i2 - o * 384;
            BmatT[(768 + o) * 384 + kk] = f2b(lW[kk * 2 + o]);
            return;
        }
        i2 -= 768;
        if (i2 < 768) {                      // lWtT [2,384] (tail-linear)
            int o = i2 / 384, ii = i2 - o * 384;
            lWtT[o * 384 + ii] = f2b(lW[(384 + ii) * 2 + o]);
        }
        return;
    }

    int r = pb - NB_PREP;                    // transposes
    const float* src; ushort_t* dst; int Rr, Cc, xs;
    if (r < 576)        { src = hW1;          dst = hW1T;  Rr = 768; Cc = 768; xs = 24; }
    else if (r < 1152)  { r -= 576;  src = tW1;          dst = tW1T;  Rr = 768; Cc = 768; xs = 24; }
    else if (r < 1440)  { r -= 1152; src = hW2;          dst = hW2T;  Rr = 768; Cc = 384; xs = 24; }
    else if (r < 1728)  { r -= 1440; src = tW2;          dst = tW2T;  Rr = 768; Cc = 384; xs = 24; }
    else if (r < 1872)  { r -= 1728; src = bil;          dst = BmatT; Rr = 384; Cc = 384; xs = 12; }
    else                { r -= 1872; src = bil + 147456; dst = BmatT + 147456; Rr = 384; Cc = 384; xs = 12; }
    int bx = r % xs, by = r / xs;
    int tR = bx * 32, tC = by * 32;
    int tx = tid & 31, ty = tid >> 5;        // ty in [0,8)
#pragma unroll
    for (int rr = 0; rr < 4; ++rr)
        smem[(ty + rr * 8) * 33 + tx] = src[(size_t)(tR + ty + rr * 8) * Cc + tC + tx];
    __syncthreads();
#pragma unroll
    for (int rr = 0; rr < 4; ++rr)
        dst[(size_t)(tC + ty + rr * 8) * Rr + tR + tx] = f2b(smem[tx * 33 + ty + rr * 8]);
}

// ---------------------------------------------------------------------------
// LDS-staged bf16 MFMA GEMM, 64xBN block tile (template BN in {64,32}),
// BK=64, one barrier per K-step, 2-deep double buffer (R6-proven loop;
// R7's counted-vmcnt 3-buffer variant REGRESSED and is reverted).
// ROUND-8: GEMM3 moves to BN=32 so its useful-block count goes 448 -> 832
// (1.75 -> 3.25 blocks/CU) -- same balance mechanism that won R6 (-5.6us).
// Staging: LDS dest is wave-uniform base + lane*16B (m104/m108); global
// source segment pre-swizzled gseg = (lane&7)^(lane>>3) == phys^(row&7);
// ds_read at row*64 + ((ks*4+quad)^(row&7))*8 -> conflict-free b128 at
// 128-B row stride. __syncthreads()'s implicit vmcnt(0)+lgkmcnt(0) drain
// makes the dbuf hand-off race-free. A [M,K] row-major, Bt [N,K] row-major.
// blockIdx.z selects operand set. OOB B-row staging (tileN near N) reads
// adjacent allocated ws; results masked by gc<N store guard.
// ---------------------------------------------------------------------------
#define GLL16(src, dst) __builtin_amdgcn_global_load_lds( \
    (const __attribute__((address_space(1))) void*)(src), \
    (__attribute__((address_space(3))) void*)(dst), 16, 0, 0)

template<int BN>
__global__ __launch_bounds__(256) void gemm_lds(
    const ushort_t* __restrict__ A0, const ushort_t* __restrict__ A1,
    const ushort_t* __restrict__ Bt0, const ushort_t* __restrict__ Bt1,
    const float* __restrict__ bias0, const float* __restrict__ bias1,
    void* __restrict__ out0, void* __restrict__ out1,
    const int* __restrict__ lab,
    int M, int N0, int N1, int K, int doRelu, int f32o0, int f32o1)
{
    constexpr int NI   = BN / 32;            // n-frags per wave
    constexpr int RPWB = BN / 4;             // staged B rows per wave
    constexpr int NSTB = RPWB / 8;           // GLL16 statements for B (2 or 1)
    __shared__ ushort_t As[2][4096];
    __shared__ ushort_t Bs[2][BN * 64];
    int N = blockIdx.z ? N1 : N0;
    int tileN = blockIdx.y * BN;
    if (tileN >= N) return;
    const ushort_t* A   = blockIdx.z ? A1 : A0;
    const ushort_t* Bt  = blockIdx.z ? Bt1 : Bt0;
    const float*   bias = blockIdx.z ? bias1 : bias0;
    int           f32o  = blockIdx.z ? f32o1 : f32o0;
    ushort_t*      outH = (ushort_t*)(blockIdx.z ? out1 : out0);
    float*         outF = (float*)(blockIdx.z ? out1 : out0);

    int t = threadIdx.x;
    int lane = t & 63, wave = t >> 6;
    int tileM = blockIdx.x * 64;
    int wm = (wave >> 1) * 32, wn = (wave & 1) * (BN / 2);
    int l15 = lane & 15, quad = lane >> 4;

    // staging: statement c covers rows wave*RPW + c*8 + (lane>>3), phys slot
    // lane&7 (lane*16B pattern); global seg pre-swizzled.
    int grwA  = wave * 16 + (lane >> 3);
    int grwB  = wave * RPWB + (lane >> 3);
    int gseg8 = ((lane & 7) ^ (lane >> 3)) << 3;           // ushort offset
    const ushort_t* pA = A  + (size_t)(tileM + grwA) * K + gseg8;
    const ushort_t* pB = Bt + (size_t)(tileN + grwB) * K + gseg8;
    int ldA = wave * 1024 + lane * 8;                      // ushort offsets
    int ldB = wave * (RPWB * 64) + lane * 8;

    // swizzled ds_read offsets: row*64 + ((ks*4+quad)^(row&7))*8 ushorts
    int offA[2][2], offB[NI][2];
#pragma unroll
    for (int mi = 0; mi < 2; ++mi) {
        int rw = wm + mi * 16 + l15;
#pragma unroll
        for (int ks = 0; ks < 2; ++ks)
            offA[mi][ks] = rw * 64 + (((ks * 4 + quad) ^ (rw & 7)) << 3);
    }
#pragma unroll
    for (int ni = 0; ni < NI; ++ni) {
        int rw = wn + ni * 16 + l15;
#pragma unroll
        for (int ks = 0; ks < 2; ++ks)
            offB[ni][ks] = rw * 64 + (((ks * 4 + quad) ^ (rw & 7)) << 3);
    }

    f32x4 acc[2][NI];
#pragma unroll
    for (int a = 0; a < 2; ++a)
#pragma unroll
        for (int b = 0; b < NI; ++b) {
            acc[a][b][0] = 0.f; acc[a][b][1] = 0.f;
            acc[a][b][2] = 0.f; acc[a][b][3] = 0.f;
        }

    // prologue: stage tile 0 into buffer 0
    GLL16(pA, &As[0][ldA]);
    GLL16(pA + (size_t)8 * K, &As[0][ldA + 512]);
#pragma unroll
    for (int c = 0; c < NSTB; ++c)
        GLL16(pB + (size_t)(c * 8) * K, &Bs[0][ldB + c * 512]);
    __syncthreads();

    int nk = K >> 6;
    for (int kt = 0; kt < nk; ++kt) {
        int cur = kt & 1;
        if (kt + 1 < nk) {                   // issue next-tile stage early
            int ko = (kt + 1) << 6;
            GLL16(pA + ko, &As[cur ^ 1][ldA]);
            GLL16(pA + (size_t)8 * K + ko, &As[cur ^ 1][ldA + 512]);
#pragma unroll
            for (int c = 0; c < NSTB; ++c)
                GLL16(pB + (size_t)(c * 8) * K + ko, &Bs[cur ^ 1][ldB + c * 512]);
        }
#pragma unroll
        for (int ks = 0; ks < 2; ++ks) {
            bf16x8 bfr[NI];
#pragma unroll
            for (int ni = 0; ni < NI; ++ni)
                bfr[ni] = *reinterpret_cast<const bf16x8*>(&Bs[cur][offB[ni][ks]]);
#pragma unroll
            for (int mi = 0; mi < 2; ++mi) {
                bf16x8 af = *reinterpret_cast<const bf16x8*>(&As[cur][offA[mi][ks]]);
#pragma unroll
                for (int ni = 0; ni < NI; ++ni)
                    acc[mi][ni] = __builtin_amdgcn_mfma_f32_16x16x32_bf16(af, bfr[ni], acc[mi][ni], 0, 0, 0);
            }
        }
        __syncthreads();                     // drains vmcnt+lgkmcnt: next tile
    }                                        // ready, current buffer consumed

#pragma unroll
    for (int mi = 0; mi < 2; ++mi) {
        int gr = tileM + wm + mi * 16 + quad * 4;
        int lb4[4];
        if (lab) {
#pragma unroll
            for (int r = 0; r < 4; ++r) lb4[r] = lab[gr + r];
        }
#pragma unroll
        for (int ni = 0; ni < NI; ++ni) {
            int gc = tileN + wn + ni * 16 + l15;
            if (gc < N) {
#pragma unroll
                for (int r = 0; r < 4; ++r) {
                    float bb = lab ? bias[(size_t)lb4[r] * N + gc]
                                   : (bias ? bias[gc] : 0.0f);
                    float v = acc[mi][ni][r] + bb;
                    if (doRelu) v = fmaxf(v, 0.0f);
                    if (f32o) outF[(size_t)(gr + r) * N + gc] = v;
                    else      outH[(size_t)(gr + r) * N + gc] = f2b(v);
                }
            }
        }
    }
}

// ---------------------------------------------------------------------------
// Per-relation: logits + log-softmax + loss. ROUND-8: 4 relations per wave
// (was 8), 2048 blocks = 8/CU, 32 waves/CU -- halves each wave's serial
// chain of gathered-L2-load -> 12-shuffle reductions, doubles TLP.
// Tail-linear term precomputed per ENTITY (tLin, f32).
// ---------------------------------------------------------------------------
__global__ __launch_bounds__(256) void rel_kernel(
    const ushort_t* __restrict__ Uext, const ushort_t* __restrict__ tailsE,
    const float* __restrict__ tLin, const float* __restrict__ lb,
    const int* __restrict__ rel_head, const int* __restrict__ rel_tail,
    const int* __restrict__ rel_label, float* __restrict__ out)
{
    __shared__ float wsum[4];
    int lane = threadIdx.x & 63, wave = threadIdx.x >> 6;
    float lb0 = lb[0], lb1 = lb[1];
    float lossAcc = 0.0f;
    int base = (blockIdx.x * 4 + wave) * 4;

    for (int q = 0; q < 4; ++q) {
        int rel = base + q;
        int b = rel >> 11;                    // R = 2048
        int h = rel_head[rel], t = rel_tail[rel], lab = rel_label[rel];
        const uint32_t* uh = reinterpret_cast<const uint32_t*>(Uext + (size_t)(b * E_ + h) * 770);
        const uint32_t* tv = reinterpret_cast<const uint32_t*>(tailsE + (size_t)(b * E_ + t) * 384);

        float a0 = 0.f, a1 = 0.f;
#pragma unroll
        for (int j = 0; j < 3; ++j) {
            int i = lane + 64 * j;
            uint32_t tu = tv[i];
            uint32_t u0 = uh[i], u1 = uh[192 + i];
            float tl = bl(tu), th = bh(tu);
            a0 += tl * bl(u0) + th * bh(u0);
            a1 += tl * bl(u1) + th * bh(u1);
        }
#pragma unroll
        for (int d = 1; d < 64; d <<= 1) {
            a0 += __shfl_xor(a0, d);
            a1 += __shfl_xor(a1, d);
        }
        const ushort_t* uhs = reinterpret_cast<const ushort_t*>(uh);
        float2 tp = reinterpret_cast<const float2*>(tLin)[b * E_ + t];
        float l0v = a0 + tp.x + b2f(uhs[768]) + lb0;
        float l1v = a1 + tp.y + b2f(uhs[769]) + lb1;
        if (lane == 0) {
            out[1 + 2 * rel]     = l0v;
            out[1 + 2 * rel + 1] = l1v;
        }
        float m = fmaxf(l0v, l1v);
        float lse = m + logf(expf(l0v - m) + expf(l1v - m));
        lossAcc += lse - (lab ? l1v : l0v);
    }
    if (lane == 0) wsum[wave] = lossAcc;
    __syncthreads();
    if (threadIdx.x == 0) {
        float s = wsum[0] + wsum[1] + wsum[2] + wsum[3];
        atomicAdd(out, s * (1.0f / 32768.0f));
    }
}

// ---------------------------------------------------------------------------
extern "C" void kernel_launch(void* const* d_in, const int* in_sizes, int n_in,
                              void* d_out, int out_size, void* d_ws, size_t ws_size,
                              hipStream_t stream)
{
    const float* hidden = (const float*)d_in[0];
    const float* emb    = (const float*)d_in[1];
    const float* hW1    = (const float*)d_in[2];
    const float* hb1    = (const float*)d_in[3];
    const float* hW2    = (const float*)d_in[4];
    const float* hb2    = (const float*)d_in[5];
    const float* tW1    = (const float*)d_in[6];
    const float* tb1    = (const float*)d_in[7];
    const float* tW2    = (const float*)d_in[8];
    const float* tb2    = (const float*)d_in[9];
    const float* bil    = (const float*)d_in[10];
    const float* lW     = (const float*)d_in[11];
    const float* lb     = (const float*)d_in[12];
    const int* ent_start = (const int*)d_in[13];
    const int* ent_label = (const int*)d_in[14];
    const int* rel_head  = (const int*)d_in[15];
    const int* rel_tail  = (const int*)d_in[16];
    const int* rel_label = (const int*)d_in[17];
    float* out = (float*)d_out;

    char* ws = (char*)d_ws;
    ushort_t* repE   = (ushort_t*)(ws + 0);         // [2048,768]
    ushort_t* hW1T   = (ushort_t*)(ws + 3145728);   // [768,768]  (top half only)
    ushort_t* tW1T   = (ushort_t*)(ws + 4325376);   // [768,768]
    ushort_t* hW2T   = (ushort_t*)(ws + 5505024);   // [384,768]
    ushort_t* tW2T   = (ushort_t*)(ws + 6094848);   // [384,768]
    ushort_t* BmatT  = (ushort_t*)(ws + 6684672);   // [770,384]
    ushort_t* lWtT   = (ushort_t*)(ws + 7276032);   // [2,384]
    float*    biasEh = (float*)   (ws + 7277568);   // [3,768] f32
    float*    biasEt = (float*)   (ws + 7286784);   // [3,768] f32
    float*    tLin   = (float*)   (ws + 7296000);   // [2048,2] f32
    ushort_t* h1     = (ushort_t*)(ws + 7312384);   // [2048,768]
    ushort_t* t1     = (ushort_t*)(ws + 10458112);  // [2048,768]
    ushort_t* headsE = (ushort_t*)(ws + 13603840);  // [2048,384]
    ushort_t* tailsE = (ushort_t*)(ws + 15176704);  // [2048,384]
    ushort_t* Uext   = (ushort_t*)(ws + 16749568);  // [2048,770]

    prep_fused<<<3582, 256, 0, stream>>>(
        hidden, emb, lW, hW1, tW1, hW2, tW2, bil, hb1, tb1, ent_start,
        repE, hW1T, tW1T, hW2T, tW2T, BmatT, lWtT, biasEh, biasEt, out);

    // tower-1: h1/t1 = relu(hid @ W1_top + biasE[lab])  (K=768, 768 blocks)
    gemm_lds<64><<<dim3(32, 12, 2), 256, 0, stream>>>(
        repE, repE, hW1T, tW1T, biasEh, biasEt, h1, t1, ent_label,
        2048, 768, 768, 768, 1, 0, 0);

    // tower-2: heads/tails = relu(h @ W2 + b2)  (BN=32 -> 768 blocks, 3/CU)
    gemm_lds<32><<<dim3(32, 12, 2), 256, 0, stream>>>(
        h1, t1, hW2T, tW2T, hb2, tb2, headsE, tailsE, nullptr,
        2048, 384, 384, 768, 1, 0, 0);

    // z=0: Uext = heads @ [bil0^T | bil1^T | lW_head]  (bf16, BN=32 ->
    //      25 y-blocks, 800 useful blocks)
    // z=1: tLin = tails @ lW_tail^T                    (f32, [2048,2])
    gemm_lds<32><<<dim3(32, 25, 2), 256, 0, stream>>>(
        headsE, tailsE, BmatT, lWtT, nullptr, nullptr, Uext, tLin, nullptr,
        2048, 770, 2, 384, 0, 0, 1);

    rel_kernel<<<2048, 256, 0, stream>>>(
        Uext, tailsE, tLin, lb, rel_head, rel_tail, rel_label, out);
}

// Round 9
// 166.313 us; speedup vs baseline: 1.0733x; 1.0733x over previous
//
#include <hip/hip_runtime.h>
#include <hip/hip_bf16.h>
#include <cstdint>

typedef unsigned short ushort_t;
typedef __bf16 bf16x8 __attribute__((ext_vector_type(8)));
typedef float f32x4 __attribute__((ext_vector_type(4)));

#define B_   16
#define S_   512
#define D_   768
#define E_   128
#define R_   2048
#define NREL 32768

__device__ inline ushort_t f2b(float f) {
    uint32_t u = __builtin_bit_cast(uint32_t, f);
    uint32_t r = (u + 0x7fffu + ((u >> 16) & 1u)) >> 16;   // RNE
    return (ushort_t)r;
}
__device__ inline float b2f(ushort_t u) {
    uint32_t v = ((uint32_t)u) << 16;
    return __builtin_bit_cast(float, v);
}
__device__ inline float bl(uint32_t u) {
    uint32_t v = u << 16;
    return __builtin_bit_cast(float, v);
}
__device__ inline float bh(uint32_t u) {
    uint32_t v = u & 0xffff0000u;
    return __builtin_bit_cast(float, v);
}

// ---------------------------------------------------------------------------
// Fused prep: one dispatch replaces prep_kernel + transpose_w.
// Block ranges (dispatch order -> biasE latency-stragglers start first):
//   [0,24):    biasE[l] = b1 + emb[l] @ W1_bottom (full-K per block)
//   [24,1566): repE float4 gather -> bf16, BmatT rows 768/769, lWtT, out[0]=0
//   [1566,3582): six 32x32-tiled fp32->bf16 transposes (W1-top, W2, bil)
// ---------------------------------------------------------------------------
#define NB_BIAS 24
#define NB_PREP 1542

__global__ __launch_bounds__(256) void prep_fused(
    const float* __restrict__ hidden, const float* __restrict__ emb,
    const float* __restrict__ lW,
    const float* __restrict__ hW1, const float* __restrict__ tW1,
    const float* __restrict__ hW2, const float* __restrict__ tW2,
    const float* __restrict__ bil,
    const float* __restrict__ hb1, const float* __restrict__ tb1,
    const int* __restrict__ ent_start,
    ushort_t* __restrict__ repE,
    ushort_t* __restrict__ hW1T, ushort_t* __restrict__ tW1T,
    ushort_t* __restrict__ hW2T, ushort_t* __restrict__ tW2T,
    ushort_t* __restrict__ BmatT, ushort_t* __restrict__ lWtT,
    float* __restrict__ biasEh, float* __restrict__ biasEt,
    float* __restrict__ out)
{
    __shared__ float smem[3072];
    int bid = blockIdx.x;
    int tid = threadIdx.x;

    if (bid < NB_BIAS) {
        // 12 col-blocks of 64 cols x 2 towers; 16 k-groups of 48 rows each.
        int tower = bid / 12, cb = bid - tower * 12;
        const float* W1 = tower ? tW1 : hW1;
        const float* b1 = tower ? tb1 : hb1;
        float* dstB     = tower ? biasEt : biasEh;
        int c4 = (tid & 15) * 4;              // col quad within the 64
        int kg = tid >> 4;                    // 16 k-groups
        int col0 = cb * 64;
        const float* wp = W1 + (size_t)(768 + kg * 48) * 768 + col0 + c4;
        const float* ep = emb + kg * 48;
        float a0x = 0.f, a0y = 0.f, a0z = 0.f, a0w = 0.f;
        float a1x = 0.f, a1y = 0.f, a1z = 0.f, a1w = 0.f;
        float a2x = 0.f, a2y = 0.f, a2z = 0.f, a2w = 0.f;
#pragma unroll 8
        for (int k = 0; k < 48; ++k) {
            float4 w = *reinterpret_cast<const float4*>(wp + (size_t)k * 768);
            float e0 = ep[k], e1 = ep[768 + k], e2 = ep[1536 + k];
            a0x += e0 * w.x; a0y += e0 * w.y; a0z += e0 * w.z; a0w += e0 * w.w;
            a1x += e1 * w.x; a1y += e1 * w.y; a1z += e1 * w.z; a1w += e1 * w.w;
            a2x += e2 * w.x; a2y += e2 * w.y; a2z += e2 * w.z; a2w += e2 * w.w;
        }
        smem[kg * 192 +   0 + c4 + 0] = a0x;
        smem[kg * 192 +   0 + c4 + 1] = a0y;
        smem[kg * 192 +   0 + c4 + 2] = a0z;
        smem[kg * 192 +   0 + c4 + 3] = a0w;
        smem[kg * 192 +  64 + c4 + 0] = a1x;
        smem[kg * 192 +  64 + c4 + 1] = a1y;
        smem[kg * 192 +  64 + c4 + 2] = a1z;
        smem[kg * 192 +  64 + c4 + 3] = a1w;
        smem[kg * 192 + 128 + c4 + 0] = a2x;
        smem[kg * 192 + 128 + c4 + 1] = a2y;
        smem[kg * 192 + 128 + c4 + 2] = a2z;
        smem[kg * 192 + 128 + c4 + 3] = a2w;
        __syncthreads();
        if (tid < 192) {
            int l = tid >> 6, c = tid & 63;
            float s = 0.f;
#pragma unroll
            for (int g = 0; g < 16; ++g) s += smem[g * 192 + l * 64 + c];
            dstB[l * 768 + col0 + c] = b1[col0 + c] + s;
        }
        return;
    }

    int pb = bid - NB_BIAS;
    if (pb < NB_PREP) {
        int idx = pb * 256 + tid;
        if (idx == 0) out[0] = 0.0f;
        if (idx < 393216) {                  // repE [2048,768] via float4
            int row = idx / 192, q = idx - row * 192;
            int c = q * 4;
            int b = row >> 7;
            int st = ent_start[row];
            const float* srcp = hidden + ((size_t)(b * S_ + st) * D_ + c);
            float4 v = *reinterpret_cast<const float4*>(srcp);
            uint32_t lo = (uint32_t)f2b(v.x) | ((uint32_t)f2b(v.y) << 16);
            uint32_t hi = (uint32_t)f2b(v.z) | ((uint32_t)f2b(v.w) << 16);
            uint2 pk; pk.x = lo; pk.y = hi;
            *reinterpret_cast<uint2*>(repE + (size_t)idx * 4) = pk;
            return;
        }
        int i2 = idx - 393216;
        if (i2 < 768) {                      // BmatT rows 768/769 (head-linear)
            int o = i2 / 384, kk = i2 - o * 384;
            BmatT[(768 + o) * 384 + kk] = f2b(lW[kk * 2 + o]);
            return;
        }
        i2 -= 768;
        if (i2 < 768) {                      // lWtT [2,384] (tail-linear)
            int o = i2 / 384, ii = i2 - o * 384;
            lWtT[o * 384 + ii] = f2b(lW[(384 + ii) * 2 + o]);
        }
        return;
    }

    int r = pb - NB_PREP;                    // transposes
    const float* src; ushort_t* dst; int Rr, Cc, xs;
    if (r < 576)        { src = hW1;          dst = hW1T;  Rr = 768; Cc = 768; xs = 24; }
    else if (r < 1152)  { r -= 576;  src = tW1;          dst = tW1T;  Rr = 768; Cc = 768; xs = 24; }
    else if (r < 1440)  { r -= 1152; src = hW2;          dst = hW2T;  Rr = 768; Cc = 384; xs = 24; }
    else if (r < 1728)  { r -= 1440; src = tW2;          dst = tW2T;  Rr = 768; Cc = 384; xs = 24; }
    else if (r < 1872)  { r -= 1728; src = bil;          dst = BmatT; Rr = 384; Cc = 384; xs = 12; }
    else                { r -= 1872; src = bil + 147456; dst = BmatT + 147456; Rr = 384; Cc = 384; xs = 12; }
    int bx = r % xs, by = r / xs;
    int tR = bx * 32, tC = by * 32;
    int tx = tid & 31, ty = tid >> 5;        // ty in [0,8)
#pragma unroll
    for (int rr = 0; rr < 4; ++rr)
        smem[(ty + rr * 8) * 33 + tx] = src[(size_t)(tR + ty + rr * 8) * Cc + tC + tx];
    __syncthreads();
#pragma unroll
    for (int rr = 0; rr < 4; ++rr)
        dst[(size_t)(tC + ty + rr * 8) * Rr + tR + tx] = f2b(smem[tx * 33 + ty + rr * 8]);
}

// ---------------------------------------------------------------------------
// LDS-staged bf16 MFMA GEMM, 64xBN block tile (template BN in {64,32}),
// BK=64, one barrier per K-step, 2-deep double buffer. This is the R6
// verified-best configuration, restored byte-for-byte after R7 (counted
// vmcnt 3-buffer) and R8 (GEMM3 BN=32 + rel 4/wave) both regressed.
// Staging: LDS dest is wave-uniform base + lane*16B (m104/m108); global
// source segment pre-swizzled gseg = (lane&7)^(lane>>3) == phys^(row&7);
// ds_read at row*64 + ((ks*4+quad)^(row&7))*8 -> conflict-free b128 at
// 128-B row stride. __syncthreads()'s implicit vmcnt(0)+lgkmcnt(0) drain
// makes the dbuf hand-off race-free. A [M,K] row-major, Bt [N,K] row-major.
// blockIdx.z selects operand set.
// ---------------------------------------------------------------------------
#define GLL16(src, dst) __builtin_amdgcn_global_load_lds( \
    (const __attribute__((address_space(1))) void*)(src), \
    (__attribute__((address_space(3))) void*)(dst), 16, 0, 0)

template<int BN>
__global__ __launch_bounds__(256) void gemm_lds(
    const ushort_t* __restrict__ A0, const ushort_t* __restrict__ A1,
    const ushort_t* __restrict__ Bt0, const ushort_t* __restrict__ Bt1,
    const float* __restrict__ bias0, const float* __restrict__ bias1,
    void* __restrict__ out0, void* __restrict__ out1,
    const int* __restrict__ lab,
    int M, int N0, int N1, int K, int doRelu, int f32o0, int f32o1)
{
    constexpr int NI   = BN / 32;            // n-frags per wave
    constexpr int RPWB = BN / 4;             // staged B rows per wave
    constexpr int NSTB = RPWB / 8;           // GLL16 statements for B (2 or 1)
    __shared__ ushort_t As[2][4096];
    __shared__ ushort_t Bs[2][BN * 64];
    int N = blockIdx.z ? N1 : N0;
    int tileN = blockIdx.y * BN;
    if (tileN >= N) return;
    const ushort_t* A   = blockIdx.z ? A1 : A0;
    const ushort_t* Bt  = blockIdx.z ? Bt1 : Bt0;
    const float*   bias = blockIdx.z ? bias1 : bias0;
    int           f32o  = blockIdx.z ? f32o1 : f32o0;
    ushort_t*      outH = (ushort_t*)(blockIdx.z ? out1 : out0);
    float*         outF = (float*)(blockIdx.z ? out1 : out0);

    int t = threadIdx.x;
    int lane = t & 63, wave = t >> 6;
    int tileM = blockIdx.x * 64;
    int wm = (wave >> 1) * 32, wn = (wave & 1) * (BN / 2);
    int l15 = lane & 15, quad = lane >> 4;

    // staging: statement c covers rows wave*RPW + c*8 + (lane>>3), phys slot
    // lane&7 (lane*16B pattern); global seg pre-swizzled.
    int grwA  = wave * 16 + (lane >> 3);
    int grwB  = wave * RPWB + (lane >> 3);
    int gseg8 = ((lane & 7) ^ (lane >> 3)) << 3;           // ushort offset
    const ushort_t* pA = A  + (size_t)(tileM + grwA) * K + gseg8;
    const ushort_t* pB = Bt + (size_t)(tileN + grwB) * K + gseg8;
    int ldA = wave * 1024 + lane * 8;                      // ushort offsets
    int ldB = wave * (RPWB * 64) + lane * 8;

    // swizzled ds_read offsets: row*64 + ((ks*4+quad)^(row&7))*8 ushorts
    int offA[2][2], offB[NI][2];
#pragma unroll
    for (int mi = 0; mi < 2; ++mi) {
        int rw = wm + mi * 16 + l15;
#pragma unroll
        for (int ks = 0; ks < 2; ++ks)
            offA[mi][ks] = rw * 64 + (((ks * 4 + quad) ^ (rw & 7)) << 3);
    }
#pragma unroll
    for (int ni = 0; ni < NI; ++ni) {
        int rw = wn + ni * 16 + l15;
#pragma unroll
        for (int ks = 0; ks < 2; ++ks)
            offB[ni][ks] = rw * 64 + (((ks * 4 + quad) ^ (rw & 7)) << 3);
    }

    f32x4 acc[2][NI];
#pragma unroll
    for (int a = 0; a < 2; ++a)
#pragma unroll
        for (int b = 0; b < NI; ++b) {
            acc[a][b][0] = 0.f; acc[a][b][1] = 0.f;
            acc[a][b][2] = 0.f; acc[a][b][3] = 0.f;
        }

    // prologue: stage tile 0 into buffer 0
    GLL16(pA, &As[0][ldA]);
    GLL16(pA + (size_t)8 * K, &As[0][ldA + 512]);
#pragma unroll
    for (int c = 0; c < NSTB; ++c)
        GLL16(pB + (size_t)(c * 8) * K, &Bs[0][ldB + c * 512]);
    __syncthreads();

    int nk = K >> 6;
    for (int kt = 0; kt < nk; ++kt) {
        int cur = kt & 1;
        if (kt + 1 < nk) {                   // issue next-tile stage early
            int ko = (kt + 1) << 6;
            GLL16(pA + ko, &As[cur ^ 1][ldA]);
            GLL16(pA + (size_t)8 * K + ko, &As[cur ^ 1][ldA + 512]);
#pragma unroll
            for (int c = 0; c < NSTB; ++c)
                GLL16(pB + (size_t)(c * 8) * K + ko, &Bs[cur ^ 1][ldB + c * 512]);
        }
#pragma unroll
        for (int ks = 0; ks < 2; ++ks) {
            bf16x8 bfr[NI];
#pragma unroll
            for (int ni = 0; ni < NI; ++ni)
                bfr[ni] = *reinterpret_cast<const bf16x8*>(&Bs[cur][offB[ni][ks]]);
#pragma unroll
            for (int mi = 0; mi < 2; ++mi) {
                bf16x8 af = *reinterpret_cast<const bf16x8*>(&As[cur][offA[mi][ks]]);
#pragma unroll
                for (int ni = 0; ni < NI; ++ni)
                    acc[mi][ni] = __builtin_amdgcn_mfma_f32_16x16x32_bf16(af, bfr[ni], acc[mi][ni], 0, 0, 0);
            }
        }
        __syncthreads();                     // drains vmcnt+lgkmcnt: next tile
    }                                        // ready, current buffer consumed

#pragma unroll
    for (int mi = 0; mi < 2; ++mi) {
        int gr = tileM + wm + mi * 16 + quad * 4;
        int lb4[4];
        if (lab) {
#pragma unroll
            for (int r = 0; r < 4; ++r) lb4[r] = lab[gr + r];
        }
#pragma unroll
        for (int ni = 0; ni < NI; ++ni) {
            int gc = tileN + wn + ni * 16 + l15;
            if (gc < N) {
#pragma unroll
                for (int r = 0; r < 4; ++r) {
                    float bb = lab ? bias[(size_t)lb4[r] * N + gc]
                                   : (bias ? bias[gc] : 0.0f);
                    float v = acc[mi][ni][r] + bb;
                    if (doRelu) v = fmaxf(v, 0.0f);
                    if (f32o) outF[(size_t)(gr + r) * N + gc] = v;
                    else      outH[(size_t)(gr + r) * N + gc] = f2b(v);
                }
            }
        }
    }
}

// ---------------------------------------------------------------------------
// Per-relation: logits + log-softmax + loss. One wave per 8 relations.
// Tail-linear term precomputed per ENTITY (tLin, f32). (R6 configuration.)
// ---------------------------------------------------------------------------
__global__ __launch_bounds__(256) void rel_kernel(
    const ushort_t* __restrict__ Uext, const ushort_t* __restrict__ tailsE,
    const float* __restrict__ tLin, const float* __restrict__ lb,
    const int* __restrict__ rel_head, const int* __restrict__ rel_tail,
    const int* __restrict__ rel_label, float* __restrict__ out)
{
    __shared__ float wsum[4];
    int lane = threadIdx.x & 63, wave = threadIdx.x >> 6;
    float lb0 = lb[0], lb1 = lb[1];
    float lossAcc = 0.0f;
    int base = (blockIdx.x * 4 + wave) * 8;

    for (int q = 0; q < 8; ++q) {
        int rel = base + q;
        int b = rel >> 11;                    // R = 2048
        int h = rel_head[rel], t = rel_tail[rel], lab = rel_label[rel];
        const uint32_t* uh = reinterpret_cast<const uint32_t*>(Uext + (size_t)(b * E_ + h) * 770);
        const uint32_t* tv = reinterpret_cast<const uint32_t*>(tailsE + (size_t)(b * E_ + t) * 384);

        float a0 = 0.f, a1 = 0.f;
#pragma unroll
        for (int j = 0; j < 3; ++j) {
            int i = lane + 64 * j;
            uint32_t tu = tv[i];
            uint32_t u0 = uh[i], u1 = uh[192 + i];
            float tl = bl(tu), th = bh(tu);
            a0 += tl * bl(u0) + th * bh(u0);
            a1 += tl * bl(u1) + th * bh(u1);
        }
#pragma unroll
        for (int d = 1; d < 64; d <<= 1) {
            a0 += __shfl_xor(a0, d);
            a1 += __shfl_xor(a1, d);
        }
        const ushort_t* uhs = reinterpret_cast<const ushort_t*>(uh);
        float2 tp = reinterpret_cast<const float2*>(tLin)[b * E_ + t];
        float l0v = a0 + tp.x + b2f(uhs[768]) + lb0;
        float l1v = a1 + tp.y + b2f(uhs[769]) + lb1;
        if (lane == 0) {
            out[1 + 2 * rel]     = l0v;
            out[1 + 2 * rel + 1] = l1v;
        }
        float m = fmaxf(l0v, l1v);
        float lse = m + logf(expf(l0v - m) + expf(l1v - m));
        lossAcc += lse - (lab ? l1v : l0v);
    }
    if (lane == 0) wsum[wave] = lossAcc;
    __syncthreads();
    if (threadIdx.x == 0) {
        float s = wsum[0] + wsum[1] + wsum[2] + wsum[3];
        atomicAdd(out, s * (1.0f / 32768.0f));
    }
}

// ---------------------------------------------------------------------------
extern "C" void kernel_launch(void* const* d_in, const int* in_sizes, int n_in,
                              void* d_out, int out_size, void* d_ws, size_t ws_size,
                              hipStream_t stream)
{
    const float* hidden = (const float*)d_in[0];
    const float* emb    = (const float*)d_in[1];
    const float* hW1    = (const float*)d_in[2];
    const float* hb1    = (const float*)d_in[3];
    const float* hW2    = (const float*)d_in[4];
    const float* hb2    = (const float*)d_in[5];
    const float* tW1    = (const float*)d_in[6];
    const float* tb1    = (const float*)d_in[7];
    const float* tW2    = (const float*)d_in[8];
    const float* tb2    = (const float*)d_in[9];
    const float* bil    = (const float*)d_in[10];
    const float* lW     = (const float*)d_in[11];
    const float* lb     = (const float*)d_in[12];
    const int* ent_start = (const int*)d_in[13];
    const int* ent_label = (const int*)d_in[14];
    const int* rel_head  = (const int*)d_in[15];
    const int* rel_tail  = (const int*)d_in[16];
    const int* rel_label = (const int*)d_in[17];
    float* out = (float*)d_out;

    char* ws = (char*)d_ws;
    ushort_t* repE   = (ushort_t*)(ws + 0);         // [2048,768]
    ushort_t* hW1T   = (ushort_t*)(ws + 3145728);   // [768,768]  (top half only)
    ushort_t* tW1T   = (ushort_t*)(ws + 4325376);   // [768,768]
    ushort_t* hW2T   = (ushort_t*)(ws + 5505024);   // [384,768]
    ushort_t* tW2T   = (ushort_t*)(ws + 6094848);   // [384,768]
    ushort_t* BmatT  = (ushort_t*)(ws + 6684672);   // [770,384]
    ushort_t* lWtT   = (ushort_t*)(ws + 7276032);   // [2,384]
    float*    biasEh = (float*)   (ws + 7277568);   // [3,768] f32
    float*    biasEt = (float*)   (ws + 7286784);   // [3,768] f32
    float*    tLin   = (float*)   (ws + 7296000);   // [2048,2] f32
    ushort_t* h1     = (ushort_t*)(ws + 7312384);   // [2048,768]
    ushort_t* t1     = (ushort_t*)(ws + 10458112);  // [2048,768]
    ushort_t* headsE = (ushort_t*)(ws + 13603840);  // [2048,384]
    ushort_t* tailsE = (ushort_t*)(ws + 15176704);  // [2048,384]
    ushort_t* Uext   = (ushort_t*)(ws + 16749568);  // [2048,770]

    prep_fused<<<3582, 256, 0, stream>>>(
        hidden, emb, lW, hW1, tW1, hW2, tW2, bil, hb1, tb1, ent_start,
        repE, hW1T, tW1T, hW2T, tW2T, BmatT, lWtT, biasEh, biasEt, out);

    // tower-1: h1/t1 = relu(hid @ W1_top + biasE[lab])  (K=768, 768 blocks)
    gemm_lds<64><<<dim3(32, 12, 2), 256, 0, stream>>>(
        repE, repE, hW1T, tW1T, biasEh, biasEt, h1, t1, ent_label,
        2048, 768, 768, 768, 1, 0, 0);

    // tower-2: heads/tails = relu(h @ W2 + b2)  (BN=32 -> 768 blocks, 3/CU)
    gemm_lds<32><<<dim3(32, 12, 2), 256, 0, stream>>>(
        h1, t1, hW2T, tW2T, hb2, tb2, headsE, tailsE, nullptr,
        2048, 384, 384, 768, 1, 0, 0);

    // z=0: Uext = heads @ [bil0^T | bil1^T | lW_head]  (bf16)
    // z=1: tLin = tails @ lW_tail^T                    (f32, [2048,2])
    gemm_lds<64><<<dim3(32, 13, 2), 256, 0, stream>>>(
        headsE, tailsE, BmatT, lWtT, nullptr, nullptr, Uext, tLin, nullptr,
        2048, 770, 2, 384, 0, 0, 1);

    rel_kernel<<<1024, 256, 0, stream>>>(
        Uext, tailsE, tLin, lb, rel_head, rel_tail, rel_label, out);
}